// Round 3
// baseline (15770.988 us; speedup 1.0000x reference)
//
#include <hip/hip_runtime.h>
#include <hip/hip_bf16.h>
#include <math.h>

#define D 256
#define V 50000
#define QN 4096
#define LL 64
#define NB 1024      // B
#define NBR 1024     // BR
#define OC 32
#define G4 1024      // 4*D

// workspace float offsets
#define OFF_H    0ull                   // 4 rec * 2 parity * QN * D = 8,388,608
#define OFF_C    8388608ull             // 4 rec * QN * D = 4,194,304
#define OFF_SC   12582912ull            // 16 floats: S1,S2,NE,...
#define OFF_WB   12582928ull            // 4 * 512 * 1024 = 2,097,152
#define OFF_BB   14680080ull            // 4 * 1024
#define ZERO_F4  3145732ull             // (H + C + SC) / 4 exactly

__device__ __forceinline__ float sigf(float x){ return 1.0f/(1.0f+__expf(-x)); }
__device__ __forceinline__ float tanhf_(float x){ return 1.0f - 2.0f/(__expf(2.0f*x)+1.0f); }
__device__ __forceinline__ float logsig(float x){
    float ax = fabsf(x);
    float r = -log1pf(expf(-ax));
    return x < 0.0f ? x + r : r;
}

__global__ void k_zero(float4* ws4){
    size_t i = (size_t)blockIdx.x*256 + threadIdx.x;
    if (i < ZERO_F4) ws4[i] = make_float4(0.f,0.f,0.f,0.f);
}

// Reorder LSTM weights into B-matrix [r][512][1024], column n = j*4 + gate,
// gate row in original = gate*256 + j. k<256 -> Wih, k>=256 -> Whh.
__global__ void k_reorder(const float* uWihF, const float* uWhhF, const float* ubF,
                          const float* uWihB, const float* uWhhB, const float* ubB,
                          const float* vWihF, const float* vWhhF, const float* vbF,
                          const float* vWihB, const float* vWhhB, const float* vbB,
                          float* WB, float* BB){
    unsigned gid = blockIdx.x*256u + threadIdx.x;
    if (gid < 4u*512u*1024u){
        unsigned r = gid >> 19, rem = gid & ((1u<<19)-1u);
        unsigned k = rem >> 10, n = rem & 1023u;
        unsigned j = n >> 2, g = n & 3u, row = g*256u + j;
        const float* Wih = (r==0)?uWihF:(r==1)?uWihB:(r==2)?vWihF:vWihB;
        const float* Whh = (r==0)?uWhhF:(r==1)?uWhhB:(r==2)?vWhhF:vWhhB;
        WB[gid] = (k < 256u) ? Wih[row*256u + k] : Whh[row*256u + (k-256u)];
    } else {
        unsigned t = gid - 4u*512u*1024u;
        if (t < 4096u){
            unsigned r = t >> 10, n = t & 1023u, j = n >> 2, g = n & 3u;
            const float* b = (r==0)?ubF:(r==1)?ubB:(r==2)?vbF:vbB;
            BB[t] = b[g*256u + j];
        }
    }
}

// One LSTM time step for all 4 recurrences. Grid 1024 blocks:
// r = bid>>8 (0:u_f 1:u_b 2:v_f 3:v_b), mt = (bid&255)>>3, nt = bid&7.
// GEMM [128 rows x K=512 x 128 gate-cols] + cell epilogue with length mask.
__global__ __launch_bounds__(256) void k_step(
    const float* __restrict__ X, const int* __restrict__ lens,
    const float* __restrict__ WB, const float* __restrict__ BB,
    float* __restrict__ H, float* __restrict__ C, int s)
{
    __shared__ float As[32][132];
    __shared__ float Bs[32][132];
    const int tid = threadIdx.x;
    const int bid = blockIdx.x;
    const int r  = bid >> 8;
    const int b2 = bid & 255;
    const int mt = b2 >> 3, nt = b2 & 7;
    const int t = (r & 1) ? (63 - s) : s;
    const float* Bw  = WB + (size_t)r*512*1024;
    const float* Hin = H + (size_t)(r*2 + (s&1))*QN*D;
    float* Hout      = H + (size_t)(r*2 + ((s+1)&1))*QN*D;
    float* Cr        = C + (size_t)r*QN*D;
    const int m0 = mt*128, n0 = nt*128;
    const int tx = tid & 15, ty = tid >> 4;

    float acc[8][8] = {};

    for (int kt = 0; kt < 16; ++kt){
        #pragma unroll
        for (int q = 0; q < 4; ++q){
            int idx = tid + q*256;
            int row = idx >> 3, k4 = idx & 7;
            int kg = kt*32 + k4*4;
            const float* src = (kg < 256)
                ? (X + ((size_t)(m0+row)*LL + t)*D + kg)
                : (Hin + (size_t)(m0+row)*D + (kg - 256));
            float4 a = *(const float4*)src;
            As[k4*4+0][row] = a.x; As[k4*4+1][row] = a.y;
            As[k4*4+2][row] = a.z; As[k4*4+3][row] = a.w;
            int krow = idx >> 5, n4 = idx & 31;
            float4 bv = *(const float4*)(Bw + (size_t)(kt*32+krow)*1024 + n0 + n4*4);
            *(float4*)&Bs[krow][n4*4] = bv;
        }
        __syncthreads();
        #pragma unroll 4
        for (int k = 0; k < 32; ++k){
            float a[8], b[8];
            *(float4*)&a[0] = *(const float4*)&As[k][ty*8];
            *(float4*)&a[4] = *(const float4*)&As[k][ty*8+4];
            *(float4*)&b[0] = *(const float4*)&Bs[k][tx*8];
            *(float4*)&b[4] = *(const float4*)&Bs[k][tx*8+4];
            #pragma unroll
            for (int i = 0; i < 8; ++i)
                #pragma unroll
                for (int j = 0; j < 8; ++j)
                    acc[i][j] = fmaf(a[i], b[j], acc[i][j]);
        }
        __syncthreads();
    }

    // epilogue: LSTM cell (torch gate order i,f,g,o) + mask (t < len)
    #pragma unroll
    for (int i = 0; i < 8; ++i){
        int gm = m0 + ty*8 + i;
        int len = lens[gm];
        bool msk = (t < len);
        #pragma unroll
        for (int jj = 0; jj < 2; ++jj){
            int nb = n0 + tx*8 + jj*4;
            float gi = acc[i][jj*4+0] + BB[r*1024 + nb + 0];
            float gf = acc[i][jj*4+1] + BB[r*1024 + nb + 1];
            float gg = acc[i][jj*4+2] + BB[r*1024 + nb + 2];
            float go = acc[i][jj*4+3] + BB[r*1024 + nb + 3];
            int jh = nt*32 + tx*2 + jj;
            size_t ci = (size_t)gm*D + jh;
            float c_old = Cr[ci];
            float c2 = sigf(gf)*c_old + sigf(gi)*tanhf_(gg);
            float h2 = sigf(go)*tanhf_(c2);
            if (msk){ Cr[ci] = c2; Hout[ci] = h2; }
            else    { Hout[ci] = Hin[ci]; }
        }
    }
}

// Network-embedding part: per-b partial sums of S1 = sum(eu*ev), S2 = sum(nv*eu)
__global__ __launch_bounds__(256) void k_ne(
    const float* __restrict__ H,
    const float* __restrict__ ru, const float* __restrict__ rv,
    const float* __restrict__ au, const float* __restrict__ av,
    const int* rpu, const int* rpv, const int* rpn,
    const int* apu, const int* apv, const int* apn,
    const int* qpu, const int* qpv, const int* qpn,
    const int* nsamp, float* SC)
{
    int b = blockIdx.x, d = threadIdx.x;
    const float* Huf = H + 0ull*QN*D;
    const float* Hub = H + 2ull*QN*D;
    const float* Hvf = H + 4ull*QN*D;
    const float* Hvb = H + 6ull*QN*D;
    float eu = ru[(size_t)rpu[b]*D + d] + au[(size_t)apu[b]*D + d]
             + Huf[(size_t)qpu[b]*D + d] + Hub[(size_t)qpu[b]*D + d];
    float ev = rv[(size_t)rpv[b]*D + d] + av[(size_t)apv[b]*D + d]
             + Hvf[(size_t)qpv[b]*D + d] + Hvb[(size_t)qpv[b]*D + d];
    float s1 = eu*ev;
    float s2 = 0.f;
    int K = nsamp[0];
    for (int k = 0; k < K; ++k){
        int o = b*K + k;
        float nv = rv[(size_t)rpn[o]*D + d] + av[(size_t)apn[o]*D + d]
                 + Hvf[(size_t)qpn[o]*D + d] + Hvb[(size_t)qpn[o]*D + d];
        s2 += nv*eu;
    }
    __shared__ float red[256];
    red[d] = s1; __syncthreads();
    for (int st = 128; st > 0; st >>= 1){ if (d < st) red[d] += red[d+st]; __syncthreads(); }
    float t1 = red[0]; __syncthreads();
    red[d] = s2; __syncthreads();
    for (int st = 128; st > 0; st >>= 1){ if (d < st) red[d] += red[d+st]; __syncthreads(); }
    if (d == 0){ atomicAdd(&SC[0], t1); atomicAdd(&SC[1], red[0]); }
}

__global__ void k_nef(float* SC){
    if (threadIdx.x == 0 && blockIdx.x == 0)
        SC[2] = logsig(SC[0]) + logsig(-SC[1]);
}

// Ranking part: one block per b. rows: 0=er 1=eq 2=ea 3=eacc.
__global__ __launch_bounds__(256) void k_rank(
    const float* __restrict__ H, const float* __restrict__ ru, const float* __restrict__ au,
    const int* rr, const int* ra, const int* racc, const int* rq,
    const float* k1, const float* cb1, const float* k2, const float* cb2,
    const float* k3, const float* cb3,
    const float* f1w, const float* f1b, const float* f2w, const float* f2b,
    const float* f3w, const float* f3b,
    const float* SC, float* out)
{
    int b = blockIdx.x, tid = threadIdx.x;
    __shared__ float rows[4][D];
    __shared__ float d1[4][32], d2[3][32], d3[2][32];
    __shared__ float lred[32], hred[32];
    {
        int d = tid;
        const float* Huf = H;
        const float* Hub = H + 2ull*QN*D;
        rows[0][d] = ru[(size_t)rr[b]*D + d];
        rows[1][d] = Huf[(size_t)rq[b]*D + d] + Hub[(size_t)rq[b]*D + d];
        rows[2][d] = au[(size_t)ra[b]*D + d];
        rows[3][d] = au[(size_t)racc[b]*D + d];
    }
    __syncthreads();
    // 288 dot products: 128 (c1, len256) + 96 (c2, len512) + 64 (c3, len768)
    for (int pass = 0; pass < 2; ++pass){
        int id = tid + pass*256;
        if (id < 288){
            if (id < 128){
                int h = id >> 5, c = id & 31;
                const float* kr = k1 + c*D;
                float s = 0.f;
                for (int d0 = 0; d0 < D; ++d0) s += rows[h][d0]*kr[d0];
                d1[h][c] = s;
            } else if (id < 224){
                int p = (id-128) >> 5, c = id & 31;
                int A = (p==0)?0:1;
                int Bb = (p==0)?1:(p==1)?2:3;
                const float* kr = k2 + c*2*D;
                float s = 0.f;
                for (int d0 = 0; d0 < D; ++d0)
                    s += rows[A][d0]*kr[d0] + rows[Bb][d0]*kr[D+d0];
                d2[p][c] = s;
            } else {
                int tr = (id-224) >> 5, c = id & 31;
                int r2 = (tr==0)?2:3;
                const float* kr = k3 + c*3*D;
                float s = 0.f;
                for (int d0 = 0; d0 < D; ++d0)
                    s += rows[0][d0]*kr[d0] + rows[1][d0]*kr[D+d0] + rows[r2][d0]*kr[2*D+d0];
                d3[tr][c] = s;
            }
        }
    }
    __syncthreads();
    if (tid < 32){
        int c = tid;
        float b1 = cb1[c], b2 = cb2[c], b3 = cb3[c];
        float r0 = fmaxf(d1[0][c]+b1, 0.f), r1 = fmaxf(d1[1][c]+b1, 0.f);
        float r2 = fmaxf(d1[2][c]+b1, 0.f), r3 = fmaxf(d1[3][c]+b1, 0.f);
        float p1l = fmaxf(fmaxf(r0,r1), r2);
        float p1h = fmaxf(fmaxf(r0,r1), r3);
        float w01 = fmaxf(d2[0][c]+b2, 0.f), w12 = fmaxf(d2[1][c]+b2, 0.f), w13 = fmaxf(d2[2][c]+b2, 0.f);
        float p2l = fmaxf(w01, w12), p2h = fmaxf(w01, w13);
        float c3l = fmaxf(d3[0][c]+b3, 0.f), c3h = fmaxf(d3[1][c]+b3, 0.f);
        lred[c] = p1l*f1w[c] + p2l*f2w[c] + c3l*f3w[c];
        hred[c] = p1h*f3w[c] + p2h*f2w[c] + c3h*f3w[c];   // note: f3w on p1h (kept bug)
    }
    __syncthreads();
    if (tid == 0){
        float lo = 0.f, hi = 0.f;
        for (int c = 0; c < 32; ++c){ lo += lred[c]; hi += hred[c]; }
        lo += f1b[0] + f2b[0] + f3b[0];
        hi += f3b[0] + f2b[0] + f3b[0];                    // f3b twice (kept bug)
        out[b] = SC[2] + logsig(lo - hi);
    }
}

extern "C" void kernel_launch(void* const* d_in, const int* in_sizes, int n_in,
                              void* d_out, int out_size, void* d_ws, size_t ws_size,
                              hipStream_t stream)
{
    const float* q_texts  = (const float*)d_in[0];
    const int*   q_lens   = (const int*)d_in[1];
    const int*   rpos_u   = (const int*)d_in[2];
    const int*   rpos_v   = (const int*)d_in[3];
    const int*   rpos_neg = (const int*)d_in[4];
    const int*   apos_u   = (const int*)d_in[5];
    const int*   apos_v   = (const int*)d_in[6];
    const int*   apos_neg = (const int*)d_in[7];
    const int*   qpos_u   = (const int*)d_in[8];
    const int*   qpos_v   = (const int*)d_in[9];
    const int*   qpos_neg = (const int*)d_in[10];
    const int*   rank_r   = (const int*)d_in[11];
    const int*   rank_a   = (const int*)d_in[12];
    const int*   rank_acc = (const int*)d_in[13];
    const int*   rank_q   = (const int*)d_in[14];
    const int*   nsample  = (const int*)d_in[15];
    const float* ru_emb   = (const float*)d_in[16];
    const float* rv_emb   = (const float*)d_in[17];
    const float* au_emb   = (const float*)d_in[18];
    const float* av_emb   = (const float*)d_in[19];
    const float* uWihF = (const float*)d_in[20];
    const float* uWhhF = (const float*)d_in[21];
    const float* ubF   = (const float*)d_in[22];
    const float* uWihB = (const float*)d_in[23];
    const float* uWhhB = (const float*)d_in[24];
    const float* ubB   = (const float*)d_in[25];
    const float* vWihF = (const float*)d_in[26];
    const float* vWhhF = (const float*)d_in[27];
    const float* vbF   = (const float*)d_in[28];
    const float* vWihB = (const float*)d_in[29];
    const float* vWhhB = (const float*)d_in[30];
    const float* vbB   = (const float*)d_in[31];
    const float* k1  = (const float*)d_in[32];
    const float* cb1 = (const float*)d_in[33];
    const float* k2  = (const float*)d_in[34];
    const float* cb2 = (const float*)d_in[35];
    const float* k3  = (const float*)d_in[36];
    const float* cb3 = (const float*)d_in[37];
    const float* f1w = (const float*)d_in[38];
    const float* f1b = (const float*)d_in[39];
    const float* f2w = (const float*)d_in[40];
    const float* f2b = (const float*)d_in[41];
    const float* f3w = (const float*)d_in[42];
    const float* f3b = (const float*)d_in[43];

    float* ws = (float*)d_ws;
    float* H   = ws + OFF_H;
    float* C   = ws + OFF_C;
    float* SC  = ws + OFF_SC;
    float* WB  = ws + OFF_WB;
    float* BBb = ws + OFF_BB;

    hipLaunchKernelGGL(k_zero, dim3((unsigned)((ZERO_F4 + 255)/256)), dim3(256), 0, stream,
                       (float4*)ws);
    hipLaunchKernelGGL(k_reorder, dim3(8209), dim3(256), 0, stream,
                       uWihF,uWhhF,ubF, uWihB,uWhhB,ubB,
                       vWihF,vWhhF,vbF, vWihB,vWhhB,vbB, WB, BBb);
    for (int s = 0; s < 64; ++s)
        hipLaunchKernelGGL(k_step, dim3(1024), dim3(256), 0, stream,
                           q_texts, q_lens, WB, BBb, H, C, s);
    hipLaunchKernelGGL(k_ne, dim3(NB), dim3(256), 0, stream,
                       H, ru_emb, rv_emb, au_emb, av_emb,
                       rpos_u, rpos_v, rpos_neg, apos_u, apos_v, apos_neg,
                       qpos_u, qpos_v, qpos_neg, nsample, SC);
    hipLaunchKernelGGL(k_nef, dim3(1), dim3(64), 0, stream, SC);
    hipLaunchKernelGGL(k_rank, dim3(NBR), dim3(256), 0, stream,
                       H, ru_emb, au_emb, rank_r, rank_a, rank_acc, rank_q,
                       k1, cb1, k2, cb2, k3, cb3,
                       f1w, f1b, f2w, f2b, f3w, f3b, SC, (float*)d_out);
}

// Round 4
// 5721.137 us; speedup vs baseline: 2.7566x; 2.7566x over previous
//
#include <hip/hip_runtime.h>
#include <hip/hip_bf16.h>
#include <math.h>

#define D 256
#define QN 4096
#define LL 64
#define NB 1024      // B
#define NBR 1024     // BR

// workspace float offsets
#define OFF_H    0ull                   // 4 rec * 2 parity * QN * D = 8,388,608 floats
#define OFF_C    8388608ull             // 4 rec * QN * D = 4,194,304 floats
#define OFF_SC   12582912ull            // 16 floats
#define OFF_WH   12582928ull            // 4*1024*512 bf16 = 1,048,576 float slots
#define OFF_WL   13631504ull            // same
#define OFF_BB   14680080ull            // 4096 floats
#define ZERO_F4  3145732ull             // (H + C + SC) / 4 exactly

typedef __attribute__((ext_vector_type(8))) short short8;
typedef __attribute__((ext_vector_type(4))) float f32x4;

__device__ __forceinline__ float sigf(float x){ return 1.0f/(1.0f+__expf(-x)); }
__device__ __forceinline__ float tanhf_(float x){ return 1.0f - 2.0f/(__expf(2.0f*x)+1.0f); }
__device__ __forceinline__ float logsig(float x){
    float ax = fabsf(x);
    float r = -log1pf(expf(-ax));
    return x < 0.0f ? x + r : r;
}
// fp32 -> bf16 bits (RNE)
__device__ __forceinline__ unsigned short f2bf(float x){
    union{float f; unsigned u;} v; v.f = x;
    unsigned r = (v.u + 0x7fffu + ((v.u>>16)&1u)) >> 16;
    return (unsigned short)r;
}
__device__ __forceinline__ float bf2f(unsigned short b){
    union{unsigned u; float f;} v; v.u = ((unsigned)b)<<16; return v.f;
}

__global__ void k_zero(float4* ws4){
    size_t i = (size_t)blockIdx.x*256 + threadIdx.x;
    if (i < ZERO_F4) ws4[i] = make_float4(0.f,0.f,0.f,0.f);
}

// Build WBT_hi/lo[r][n=1024][k=512] (bf16, transposed, hi/lo split) + bias BBv[r][n].
// Column map: n -> nt=n>>7, cc=n&127, gate=cc>>5, jj=cc&31, j=nt*32+jj; torch row=gate*256+j.
__global__ void k_reorder(const float* uWihF, const float* uWhhF, const float* ubF,
                          const float* uWihB, const float* uWhhB, const float* ubB,
                          const float* vWihF, const float* vWhhF, const float* vbF,
                          const float* vWihB, const float* vWhhB, const float* vbB,
                          unsigned short* WH, unsigned short* WL, float* BBv){
    unsigned gid = blockIdx.x*256u + threadIdx.x;
    if (gid < 4u*1024u*512u){
        unsigned r = gid >> 19, rem = gid & ((1u<<19)-1u);
        unsigned n = rem >> 9, k = rem & 511u;
        unsigned nt = n >> 7, cc = n & 127u, gate = cc >> 5, jj = cc & 31u;
        unsigned j = nt*32u + jj, row = gate*256u + j;
        const float* Wih = (r==0)?uWihF:(r==1)?uWihB:(r==2)?vWihF:vWihB;
        const float* Whh = (r==0)?uWhhF:(r==1)?uWhhB:(r==2)?vWhhF:vWhhB;
        float w = (k < 256u) ? Wih[row*256u + k] : Whh[row*256u + (k-256u)];
        unsigned short hi = f2bf(w);
        float lo = w - bf2f(hi);
        WH[gid] = hi; WL[gid] = f2bf(lo);
    } else {
        unsigned t = gid - 4u*1024u*512u;
        if (t < 4096u){
            unsigned r = t >> 10, n = t & 1023u;
            unsigned nt = n >> 7, cc = n & 127u, gate = cc >> 5, jj = cc & 31u;
            unsigned j = nt*32u + jj;
            const float* b = (r==0)?ubF:(r==1)?ubB:(r==2)?vbF:vbB;
            BBv[t] = b[gate*256u + j];
        }
    }
}

// One LSTM step, all 4 recurrences, split-bf16 3-pass MFMA.
// Grid 1024: r=bid>>8, mt=(bid&255)>>3, nt=bid&7. Block tile M=128,N=128,K=512.
// 4 waves; wave w: rows [w*32, w*32+32), all 128 cols (2 mi x 8 ni fragments).
__global__ __launch_bounds__(256) void k_step(
    const float* __restrict__ X, const int* __restrict__ lens,
    const unsigned short* __restrict__ WH, const unsigned short* __restrict__ WL,
    const float* __restrict__ BBv,
    float* __restrict__ H, float* __restrict__ C, int s)
{
    __shared__ short Ah[128][40];
    __shared__ short Al[128][40];
    __shared__ short Bh[128][40];
    __shared__ short Bl[128][40];

    const int tid = threadIdx.x;
    const int bid = blockIdx.x;
    const int r  = bid >> 8;
    const int b2 = bid & 255;
    const int mt = b2 >> 3, nt = b2 & 7;
    const int t = (r & 1) ? (63 - s) : s;
    const float* Hin = H + (size_t)(r*2 + (s&1))*QN*D;
    float* Hout      = H + (size_t)(r*2 + ((s+1)&1))*QN*D;
    float* Cr        = C + (size_t)r*QN*D;
    const int m0 = mt*128, n0 = nt*128;
    const unsigned short* WHp = WH + (size_t)r*1024*512;
    const unsigned short* WLp = WL + (size_t)r*1024*512;

    const int w = tid >> 6, lane = tid & 63;
    const int lrow = lane & 15, hk = (lane >> 4) * 8;
    const int srow = tid >> 1, koff = (tid & 1) * 16;

    f32x4 acc[2][8];
    #pragma unroll
    for (int i = 0; i < 2; ++i)
        #pragma unroll
        for (int j = 0; j < 8; ++j)
            acc[i][j] = (f32x4){0.f,0.f,0.f,0.f};

    for (int kk = 0; kk < 16; ++kk){
        // ---- stage loads to regs ----
        const float* asrc = (kk < 8)
            ? (X + ((size_t)(m0+srow)*LL + t)*D + kk*32 + koff)
            : (Hin + (size_t)(m0+srow)*D + (kk*32 - 256) + koff);
        float av[16];
        #pragma unroll
        for (int q = 0; q < 4; ++q)
            *(float4*)&av[q*4] = *(const float4*)(asrc + q*4);
        union { unsigned short s[16]; uint4 q[2]; } pah, pal;
        #pragma unroll
        for (int i = 0; i < 16; ++i){
            unsigned short hi = f2bf(av[i]);
            pah.s[i] = hi;
            pal.s[i] = f2bf(av[i] - bf2f(hi));
        }
        size_t boff = ((size_t)(n0+srow))*512 + kk*32 + koff;
        uint4 bh0 = *(const uint4*)(WHp + boff);
        uint4 bh1 = *(const uint4*)(WHp + boff + 8);
        uint4 bl0 = *(const uint4*)(WLp + boff);
        uint4 bl1 = *(const uint4*)(WLp + boff + 8);

        __syncthreads();   // prev iter's ds_reads done before overwrite
        *(uint4*)&Ah[srow][koff]   = pah.q[0];
        *(uint4*)&Ah[srow][koff+8] = pah.q[1];
        *(uint4*)&Al[srow][koff]   = pal.q[0];
        *(uint4*)&Al[srow][koff+8] = pal.q[1];
        *(uint4*)&Bh[srow][koff]   = bh0;
        *(uint4*)&Bh[srow][koff+8] = bh1;
        *(uint4*)&Bl[srow][koff]   = bl0;
        *(uint4*)&Bl[srow][koff+8] = bl1;
        __syncthreads();

        // ---- fragments + MFMA ----
        short8 ah[2], al[2];
        #pragma unroll
        for (int mi = 0; mi < 2; ++mi){
            ah[mi] = *(const short8*)&Ah[w*32 + mi*16 + lrow][hk];
            al[mi] = *(const short8*)&Al[w*32 + mi*16 + lrow][hk];
        }
        #pragma unroll
        for (int ni = 0; ni < 8; ++ni){
            short8 bhf = *(const short8*)&Bh[ni*16 + lrow][hk];
            short8 blf = *(const short8*)&Bl[ni*16 + lrow][hk];
            #pragma unroll
            for (int mi = 0; mi < 2; ++mi){
                acc[mi][ni] = __builtin_amdgcn_mfma_f32_16x16x32_bf16(ah[mi], bhf, acc[mi][ni], 0,0,0);
                acc[mi][ni] = __builtin_amdgcn_mfma_f32_16x16x32_bf16(ah[mi], blf, acc[mi][ni], 0,0,0);
                acc[mi][ni] = __builtin_amdgcn_mfma_f32_16x16x32_bf16(al[mi], bhf, acc[mi][ni], 0,0,0);
            }
        }
    }

    // ---- epilogue: LSTM cell + mask. D[m][n]: m=(lane>>4)*4+reg, n=lane&15 per frag.
    const float* BBp = BBv + r*1024;
    #pragma unroll
    for (int mi = 0; mi < 2; ++mi){
        #pragma unroll
        for (int reg = 0; reg < 4; ++reg){
            int m = m0 + w*32 + mi*16 + (lane>>4)*4 + reg;
            int len = lens[m];
            bool msk = (t < len);
            #pragma unroll
            for (int jh = 0; jh < 2; ++jh){
                int jj = jh*16 + lrow;          // 0..31 within tile
                int jg = nt*32 + jj;            // hidden index 0..255
                float gi = acc[mi][0+jh][reg] + BBp[n0 + 0*32 + jj];
                float gf = acc[mi][2+jh][reg] + BBp[n0 + 1*32 + jj];
                float gg = acc[mi][4+jh][reg] + BBp[n0 + 2*32 + jj];
                float go = acc[mi][6+jh][reg] + BBp[n0 + 3*32 + jj];
                size_t ci = (size_t)m*D + jg;
                float c_old = Cr[ci];
                float c2 = sigf(gf)*c_old + sigf(gi)*tanhf_(gg);
                float h2 = sigf(go)*tanhf_(c2);
                if (msk){ Cr[ci] = c2; Hout[ci] = h2; }
                else    { Hout[ci] = Hin[ci]; }
            }
        }
    }
}

// Network-embedding part
__global__ __launch_bounds__(256) void k_ne(
    const float* __restrict__ H,
    const float* __restrict__ ru, const float* __restrict__ rv,
    const float* __restrict__ au, const float* __restrict__ av,
    const int* rpu, const int* rpv, const int* rpn,
    const int* apu, const int* apv, const int* apn,
    const int* qpu, const int* qpv, const int* qpn,
    const int* nsamp, float* SC)
{
    int b = blockIdx.x, d = threadIdx.x;
    const float* Huf = H + 0ull*QN*D;
    const float* Hub = H + 2ull*QN*D;
    const float* Hvf = H + 4ull*QN*D;
    const float* Hvb = H + 6ull*QN*D;
    float eu = ru[(size_t)rpu[b]*D + d] + au[(size_t)apu[b]*D + d]
             + Huf[(size_t)qpu[b]*D + d] + Hub[(size_t)qpu[b]*D + d];
    float ev = rv[(size_t)rpv[b]*D + d] + av[(size_t)apv[b]*D + d]
             + Hvf[(size_t)qpv[b]*D + d] + Hvb[(size_t)qpv[b]*D + d];
    float s1 = eu*ev;
    float s2 = 0.f;
    int K = nsamp[0];
    for (int k = 0; k < K; ++k){
        int o = b*K + k;
        float nv = rv[(size_t)rpn[o]*D + d] + av[(size_t)apn[o]*D + d]
                 + Hvf[(size_t)qpn[o]*D + d] + Hvb[(size_t)qpn[o]*D + d];
        s2 += nv*eu;
    }
    __shared__ float red[256];
    red[d] = s1; __syncthreads();
    for (int st = 128; st > 0; st >>= 1){ if (d < st) red[d] += red[d+st]; __syncthreads(); }
    float t1 = red[0]; __syncthreads();
    red[d] = s2; __syncthreads();
    for (int st = 128; st > 0; st >>= 1){ if (d < st) red[d] += red[d+st]; __syncthreads(); }
    if (d == 0){ atomicAdd(&SC[0], t1); atomicAdd(&SC[1], red[0]); }
}

__global__ void k_nef(float* SC){
    if (threadIdx.x == 0 && blockIdx.x == 0)
        SC[2] = logsig(SC[0]) + logsig(-SC[1]);
}

// Ranking part
__global__ __launch_bounds__(256) void k_rank(
    const float* __restrict__ H, const float* __restrict__ ru, const float* __restrict__ au,
    const int* rr, const int* ra, const int* racc, const int* rq,
    const float* k1, const float* cb1, const float* k2, const float* cb2,
    const float* k3, const float* cb3,
    const float* f1w, const float* f1b, const float* f2w, const float* f2b,
    const float* f3w, const float* f3b,
    const float* SC, float* out)
{
    int b = blockIdx.x, tid = threadIdx.x;
    __shared__ float rows[4][D];
    __shared__ float d1[4][32], d2[3][32], d3[2][32];
    __shared__ float lred[32], hred[32];
    {
        int d = tid;
        const float* Huf = H;
        const float* Hub = H + 2ull*QN*D;
        rows[0][d] = ru[(size_t)rr[b]*D + d];
        rows[1][d] = Huf[(size_t)rq[b]*D + d] + Hub[(size_t)rq[b]*D + d];
        rows[2][d] = au[(size_t)ra[b]*D + d];
        rows[3][d] = au[(size_t)racc[b]*D + d];
    }
    __syncthreads();
    for (int pass = 0; pass < 2; ++pass){
        int id = tid + pass*256;
        if (id < 288){
            if (id < 128){
                int h = id >> 5, c = id & 31;
                const float* kr = k1 + c*D;
                float sacc = 0.f;
                for (int d0 = 0; d0 < D; ++d0) sacc += rows[h][d0]*kr[d0];
                d1[h][c] = sacc;
            } else if (id < 224){
                int p = (id-128) >> 5, c = id & 31;
                int A = (p==0)?0:1;
                int Bb = (p==0)?1:(p==1)?2:3;
                const float* kr = k2 + c*2*D;
                float sacc = 0.f;
                for (int d0 = 0; d0 < D; ++d0)
                    sacc += rows[A][d0]*kr[d0] + rows[Bb][d0]*kr[D+d0];
                d2[p][c] = sacc;
            } else {
                int tr = (id-224) >> 5, c = id & 31;
                int r2 = (tr==0)?2:3;
                const float* kr = k3 + c*3*D;
                float sacc = 0.f;
                for (int d0 = 0; d0 < D; ++d0)
                    sacc += rows[0][d0]*kr[d0] + rows[1][d0]*kr[D+d0] + rows[r2][d0]*kr[2*D+d0];
                d3[tr][c] = sacc;
            }
        }
    }
    __syncthreads();
    if (tid < 32){
        int c = tid;
        float b1 = cb1[c], b2 = cb2[c], b3 = cb3[c];
        float r0 = fmaxf(d1[0][c]+b1, 0.f), r1 = fmaxf(d1[1][c]+b1, 0.f);
        float r2 = fmaxf(d1[2][c]+b1, 0.f), r3 = fmaxf(d1[3][c]+b1, 0.f);
        float p1l = fmaxf(fmaxf(r0,r1), r2);
        float p1h = fmaxf(fmaxf(r0,r1), r3);
        float w01 = fmaxf(d2[0][c]+b2, 0.f), w12 = fmaxf(d2[1][c]+b2, 0.f), w13 = fmaxf(d2[2][c]+b2, 0.f);
        float p2l = fmaxf(w01, w12), p2h = fmaxf(w01, w13);
        float c3l = fmaxf(d3[0][c]+b3, 0.f), c3h = fmaxf(d3[1][c]+b3, 0.f);
        lred[c] = p1l*f1w[c] + p2l*f2w[c] + c3l*f3w[c];
        hred[c] = p1h*f3w[c] + p2h*f2w[c] + c3h*f3w[c];   // kept reference bug
    }
    __syncthreads();
    if (tid == 0){
        float lo = 0.f, hi = 0.f;
        for (int c = 0; c < 32; ++c){ lo += lred[c]; hi += hred[c]; }
        lo += f1b[0] + f2b[0] + f3b[0];
        hi += f3b[0] + f2b[0] + f3b[0];                    // kept reference bug
        out[b] = SC[2] + logsig(lo - hi);
    }
}

extern "C" void kernel_launch(void* const* d_in, const int* in_sizes, int n_in,
                              void* d_out, int out_size, void* d_ws, size_t ws_size,
                              hipStream_t stream)
{
    const float* q_texts  = (const float*)d_in[0];
    const int*   q_lens   = (const int*)d_in[1];
    const int*   rpos_u   = (const int*)d_in[2];
    const int*   rpos_v   = (const int*)d_in[3];
    const int*   rpos_neg = (const int*)d_in[4];
    const int*   apos_u   = (const int*)d_in[5];
    const int*   apos_v   = (const int*)d_in[6];
    const int*   apos_neg = (const int*)d_in[7];
    const int*   qpos_u   = (const int*)d_in[8];
    const int*   qpos_v   = (const int*)d_in[9];
    const int*   qpos_neg = (const int*)d_in[10];
    const int*   rank_r   = (const int*)d_in[11];
    const int*   rank_a   = (const int*)d_in[12];
    const int*   rank_acc = (const int*)d_in[13];
    const int*   rank_q   = (const int*)d_in[14];
    const int*   nsample  = (const int*)d_in[15];
    const float* ru_emb   = (const float*)d_in[16];
    const float* rv_emb   = (const float*)d_in[17];
    const float* au_emb   = (const float*)d_in[18];
    const float* av_emb   = (const float*)d_in[19];
    const float* uWihF = (const float*)d_in[20];
    const float* uWhhF = (const float*)d_in[21];
    const float* ubF   = (const float*)d_in[22];
    const float* uWihB = (const float*)d_in[23];
    const float* uWhhB = (const float*)d_in[24];
    const float* ubB   = (const float*)d_in[25];
    const float* vWihF = (const float*)d_in[26];
    const float* vWhhF = (const float*)d_in[27];
    const float* vbF   = (const float*)d_in[28];
    const float* vWihB = (const float*)d_in[29];
    const float* vWhhB = (const float*)d_in[30];
    const float* vbB   = (const float*)d_in[31];
    const float* k1  = (const float*)d_in[32];
    const float* cb1 = (const float*)d_in[33];
    const float* k2  = (const float*)d_in[34];
    const float* cb2 = (const float*)d_in[35];
    const float* k3  = (const float*)d_in[36];
    const float* cb3 = (const float*)d_in[37];
    const float* f1w = (const float*)d_in[38];
    const float* f1b = (const float*)d_in[39];
    const float* f2w = (const float*)d_in[40];
    const float* f2b = (const float*)d_in[41];
    const float* f3w = (const float*)d_in[42];
    const float* f3b = (const float*)d_in[43];

    float* ws = (float*)d_ws;
    float* H   = ws + OFF_H;
    float* C   = ws + OFF_C;
    float* SC  = ws + OFF_SC;
    unsigned short* WH = (unsigned short*)(ws + OFF_WH);
    unsigned short* WL = (unsigned short*)(ws + OFF_WL);
    float* BBv = ws + OFF_BB;

    hipLaunchKernelGGL(k_zero, dim3((unsigned)((ZERO_F4 + 255)/256)), dim3(256), 0, stream,
                       (float4*)ws);
    hipLaunchKernelGGL(k_reorder, dim3(8208), dim3(256), 0, stream,
                       uWihF,uWhhF,ubF, uWihB,uWhhB,ubB,
                       vWihF,vWhhF,vbF, vWihB,vWhhB,vbB, WH, WL, BBv);
    for (int s = 0; s < 64; ++s)
        hipLaunchKernelGGL(k_step, dim3(1024), dim3(256), 0, stream,
                           q_texts, q_lens, WH, WL, BBv, H, C, s);
    hipLaunchKernelGGL(k_ne, dim3(NB), dim3(256), 0, stream,
                       H, ru_emb, rv_emb, au_emb, av_emb,
                       rpos_u, rpos_v, rpos_neg, apos_u, apos_v, apos_neg,
                       qpos_u, qpos_v, qpos_neg, nsample, SC);
    hipLaunchKernelGGL(k_nef, dim3(1), dim3(64), 0, stream, SC);
    hipLaunchKernelGGL(k_rank, dim3(NBR), dim3(256), 0, stream,
                       H, ru_emb, au_emb, rank_r, rank_a, rank_acc, rank_q,
                       k1, cb1, k2, cb2, k3, cb3,
                       f1w, f1b, f2w, f2b, f3w, f3b, SC, (float*)d_out);
}